// Round 3
// baseline (834.018 us; speedup 1.0000x reference)
//
#include <hip/hip_runtime.h>
#include <hip/hip_bf16.h>

#define TBLSZ 961   // 31*31

// ---- bf16 helpers (manual RNE, no API surprises) ----
__device__ __forceinline__ unsigned bf16rne(float x) {
    unsigned u = __float_as_uint(x);
    return (u + 0x7fffu + ((u >> 16) & 1u)) >> 16;
}
__device__ __forceinline__ unsigned packbf(float a, float b) {
    return bf16rne(a) | (bf16rne(b) << 16);
}
__device__ __forceinline__ float bflo(unsigned u) { return __uint_as_float(u << 16); }
__device__ __forceinline__ float bfhi(unsigned u) { return __uint_as_float(u & 0xffff0000u); }

// ---------------- CPB bias table: 16*sigmoid(MLP(coords)) -> [h][pos] ----------------
__global__ __launch_bounds__(512) void cpb_kernel(
    const float* __restrict__ w1, const float* __restrict__ b1,
    const float* __restrict__ w2, float* __restrict__ bias16T)
{
    const int pos = blockIdx.x;           // 0..960
    const int ia = pos / 31, ib = pos % 31;
    float va = (float)(ia - 15) * (16.0f / 15.0f);
    float vb = (float)(ib - 15) * (16.0f / 15.0f);
    float c0 = copysignf(log2f(fabsf(va) + 1.0f) * (1.0f / 3.0f), va);
    float c1 = copysignf(log2f(fabsf(vb) + 1.0f) * (1.0f / 3.0f), vb);
    const int t = threadIdx.x;
    __shared__ float hid[512];
    hid[t] = fmaxf(fmaf(w1[2*t], c0, fmaf(w1[2*t+1], c1, b1[t])), 0.0f);
    __syncthreads();
    const int h = t >> 6, l = t & 63;
    float p = 0.0f;
    #pragma unroll
    for (int i = 0; i < 8; ++i)
        p += w2[h*512 + 64*i + l] * hid[64*i + l];
    #pragma unroll
    for (int off = 32; off >= 1; off >>= 1)
        p += __shfl_down(p, off, 64);
    if (l == 0)
        bias16T[h*TBLSZ + pos] = 16.0f / (1.0f + __expf(-p));
}

// ---------------- QKV GEMM: [65536,256] @ [768,256]^T + bias -> Q/K/V [B][h][N][d] ----
__global__ __launch_bounds__(256) void qkv_gemm_kernel(
    const float* __restrict__ X, const float* __restrict__ W,
    const float* __restrict__ qb, const float* __restrict__ vbias,
    float* __restrict__ Q, float* __restrict__ K, float* __restrict__ V)
{
    __shared__ float As[16][128];
    __shared__ float Bs[16][128];
    const int m0 = blockIdx.x * 128;
    const int n0 = blockIdx.y * 128;
    const int t = threadIdx.x;
    const int tr = t >> 4, tc = t & 15;
    float4 acc[8][2];
    #pragma unroll
    for (int i = 0; i < 8; ++i) {
        acc[i][0] = make_float4(0.f,0.f,0.f,0.f);
        acc[i][1] = make_float4(0.f,0.f,0.f,0.f);
    }

    for (int k0 = 0; k0 < 256; k0 += 16) {
        __syncthreads();
        #pragma unroll
        for (int i = 0; i < 2; ++i) {
            int id = t + 256*i;
            int row = id >> 2, c4 = (id & 3) << 2;
            float4 ga = *(const float4*)&X[(m0 + row)*256 + k0 + c4];
            As[c4+0][row] = ga.x; As[c4+1][row] = ga.y;
            As[c4+2][row] = ga.z; As[c4+3][row] = ga.w;
            float4 gb = *(const float4*)&W[(n0 + row)*256 + k0 + c4];
            Bs[c4+0][row] = gb.x; Bs[c4+1][row] = gb.y;
            Bs[c4+2][row] = gb.z; Bs[c4+3][row] = gb.w;
        }
        __syncthreads();
        #pragma unroll
        for (int kk = 0; kk < 16; ++kk) {
            float4 a0 = *(const float4*)&As[kk][tr*8];
            float4 a1 = *(const float4*)&As[kk][tr*8 + 4];
            float4 b0 = *(const float4*)&Bs[kk][tc*8];
            float4 b1 = *(const float4*)&Bs[kk][tc*8 + 4];
            float av[8] = {a0.x, a0.y, a0.z, a0.w, a1.x, a1.y, a1.z, a1.w};
            #pragma unroll
            for (int ii = 0; ii < 8; ++ii) {
                acc[ii][0].x = fmaf(av[ii], b0.x, acc[ii][0].x);
                acc[ii][0].y = fmaf(av[ii], b0.y, acc[ii][0].y);
                acc[ii][0].z = fmaf(av[ii], b0.z, acc[ii][0].z);
                acc[ii][0].w = fmaf(av[ii], b0.w, acc[ii][0].w);
                acc[ii][1].x = fmaf(av[ii], b1.x, acc[ii][1].x);
                acc[ii][1].y = fmaf(av[ii], b1.y, acc[ii][1].y);
                acc[ii][1].z = fmaf(av[ii], b1.z, acc[ii][1].z);
                acc[ii][1].w = fmaf(av[ii], b1.w, acc[ii][1].w);
            }
        }
    }
    // epilogue: which block of 256 channels (q/k/v), head, dim
    const int jbase = n0 + tc*8;          // multiple of 8, uniform 'which' per block
    const int which = jbase >> 8;
    const int cin = jbase & 255;
    const int h = cin >> 5, dd = cin & 31;
    float4 bb0 = make_float4(0.f,0.f,0.f,0.f), bb1 = bb0;
    if (which == 0) {
        bb0 = *(const float4*)&qb[cin]; bb1 = *(const float4*)&qb[cin+4];
    } else if (which == 2) {
        bb0 = *(const float4*)&vbias[cin]; bb1 = *(const float4*)&vbias[cin+4];
    }
    float* dst = (which == 0) ? Q : (which == 1) ? K : V;
    #pragma unroll
    for (int ii = 0; ii < 8; ++ii) {
        int m = m0 + tr*8 + ii;
        int bwin = m >> 8, nn = m & 255;
        float* p = dst + (((bwin*8 + h)*256 + nn)*32 + dd);
        float4 o0, o1;
        o0.x = acc[ii][0].x + bb0.x; o0.y = acc[ii][0].y + bb0.y;
        o0.z = acc[ii][0].z + bb0.z; o0.w = acc[ii][0].w + bb0.w;
        o1.x = acc[ii][1].x + bb1.x; o1.y = acc[ii][1].y + bb1.y;
        o1.z = acc[ii][1].z + bb1.z; o1.w = acc[ii][1].w + bb1.w;
        *(float4*)p = o0;
        *(float4*)(p + 4) = o1;
    }
}

// ---------------- Attention: per (b,h); cosine attn + rel bias + softmax + PV --------
// AO written as bf16 in [B][N][C] layout.
__global__ __launch_bounds__(256) void attn_kernel(
    const float* __restrict__ Q, const float* __restrict__ K,
    const float* __restrict__ V, const float* __restrict__ bias16T,
    const float* __restrict__ logit_scale, unsigned* __restrict__ AO)
{
    __shared__ float tbl[TBLSZ];
    __shared__ float kt[64][32];
    __shared__ float vt[64][32];
    __shared__ float rkn[64];
    const int bh = blockIdx.x;            // b*8 + h
    const int h = bh & 7;
    const int t = threadIdx.x;
    const int n = t;                      // query row
    const float scale = __expf(fminf(logit_scale[h], 4.60517018598809136804f));
    // stage bias table slice for this head
    for (int i = t; i < TBLSZ; i += 256) tbl[i] = bias16T[h*TBLSZ + i];

    // load + normalize q row in registers
    const float* qp = Q + (bh*256 + n)*32;
    float4 qv[8];
    float ss = 0.f;
    #pragma unroll
    for (int j = 0; j < 8; ++j) {
        qv[j] = *(const float4*)(qp + 4*j);
        ss += qv[j].x*qv[j].x + qv[j].y*qv[j].y + qv[j].z*qv[j].z + qv[j].w*qv[j].w;
    }
    const float qsc = rsqrtf(fmaxf(ss, 1e-24f));
    #pragma unroll
    for (int j = 0; j < 8; ++j) {
        qv[j].x *= qsc; qv[j].y *= qsc; qv[j].z *= qsc; qv[j].w *= qsc;
    }

    float4 av[8];
    #pragma unroll
    for (int j = 0; j < 8; ++j) av[j] = make_float4(0.f,0.f,0.f,0.f);
    float sum = 0.f;
    const float off = scale + 16.0f;      // logits <= scale + 16 -> safe softmax
    const int ih = n >> 4, iw = n & 15;
    const int pbase = ih*31 + iw;

    for (int mt = 0; mt < 4; ++mt) {
        __syncthreads();
        const float* kg = K + (bh*256 + mt*64)*32;
        const float* vg = V + (bh*256 + mt*64)*32;
        #pragma unroll
        for (int i = 0; i < 2; ++i) {
            int id = t + 256*i;
            int row = id >> 3, c = (id & 7) << 2;
            *(float4*)&kt[row][c] = *(const float4*)&kg[row*32 + c];
            *(float4*)&vt[row][c] = *(const float4*)&vg[row*32 + c];
        }
        __syncthreads();
        if (t < 64) {
            float s2 = 0.f;
            #pragma unroll
            for (int j = 0; j < 8; ++j) {
                float4 g = *(const float4*)&kt[t][4*j];
                s2 += g.x*g.x + g.y*g.y + g.z*g.z + g.w*g.w;
            }
            rkn[t] = rsqrtf(fmaxf(s2, 1e-24f)) * scale;   // fold scale
        }
        __syncthreads();
        for (int mm = 0; mm < 64; ++mm) {
            const int m = mt*64 + mm;
            const int cterm = (15 - (m >> 4))*31 + (15 - (m & 15));
            const float bias = tbl[pbase + cterm];
            const float4* k4 = (const float4*)kt[mm];
            float d0 = 0.f;
            #pragma unroll
            for (int j = 0; j < 8; ++j) {
                float4 g = k4[j];
                d0 = fmaf(qv[j].x, g.x, d0); d0 = fmaf(qv[j].y, g.y, d0);
                d0 = fmaf(qv[j].z, g.z, d0); d0 = fmaf(qv[j].w, g.w, d0);
            }
            const float lg = fmaf(d0, rkn[mm], bias - off);
            const float p = __expf(lg);
            sum += p;
            const float4* v4 = (const float4*)vt[mm];
            #pragma unroll
            for (int j = 0; j < 8; ++j) {
                float4 g = v4[j];
                av[j].x = fmaf(p, g.x, av[j].x); av[j].y = fmaf(p, g.y, av[j].y);
                av[j].z = fmaf(p, g.z, av[j].z); av[j].w = fmaf(p, g.w, av[j].w);
            }
        }
    }
    const float rs = 1.0f / sum;
    // AO as bf16: 32 values per thread = 16 uints, contiguous (64B)
    unsigned ob[16];
    #pragma unroll
    for (int j = 0; j < 8; ++j) {
        ob[2*j]   = packbf(av[j].x*rs, av[j].y*rs);
        ob[2*j+1] = packbf(av[j].z*rs, av[j].w*rs);
    }
    unsigned* op = AO + (((bh >> 3)*256 + n)*8 + h)*16;
    #pragma unroll
    for (int j = 0; j < 4; ++j)
        *(uint4*)(op + 4*j) = *(uint4*)(ob + 4*j);
}

// ---------------- Proj GEMM: bf16 A [65536,256] @ fp32 W [256,256]^T + b -> out ------
__global__ __launch_bounds__(256) void proj_gemm_kernel(
    const unsigned* __restrict__ A,   // bf16 pairs, row stride 128 uints
    const float* __restrict__ W,
    const float* __restrict__ bp, float* __restrict__ out)
{
    __shared__ float As[16][128];
    __shared__ float Bs[16][128];
    const int m0 = blockIdx.x * 128;
    const int n0 = blockIdx.y * 128;
    const int t = threadIdx.x;
    const int tr = t >> 4, tc = t & 15;
    float4 acc[8][2];
    #pragma unroll
    for (int i = 0; i < 8; ++i) {
        acc[i][0] = make_float4(0.f,0.f,0.f,0.f);
        acc[i][1] = make_float4(0.f,0.f,0.f,0.f);
    }
    for (int k0 = 0; k0 < 256; k0 += 16) {
        __syncthreads();
        {   // A tile: 128 rows x 16 cols bf16 -> 256 threads x 8 elems (one uint4)
            int row = t >> 1, c8 = (t & 1) << 3;
            uint4 ga = *(const uint4*)&A[(m0 + row)*128 + (k0 + c8)/2];
            As[c8+0][row] = bflo(ga.x); As[c8+1][row] = bfhi(ga.x);
            As[c8+2][row] = bflo(ga.y); As[c8+3][row] = bfhi(ga.y);
            As[c8+4][row] = bflo(ga.z); As[c8+5][row] = bfhi(ga.z);
            As[c8+6][row] = bflo(ga.w); As[c8+7][row] = bfhi(ga.w);
        }
        #pragma unroll
        for (int i = 0; i < 2; ++i) {
            int id = t + 256*i;
            int row = id >> 2, c4 = (id & 3) << 2;
            float4 gb = *(const float4*)&W[(n0 + row)*256 + k0 + c4];
            Bs[c4+0][row] = gb.x; Bs[c4+1][row] = gb.y;
            Bs[c4+2][row] = gb.z; Bs[c4+3][row] = gb.w;
        }
        __syncthreads();
        #pragma unroll
        for (int kk = 0; kk < 16; ++kk) {
            float4 a0 = *(const float4*)&As[kk][tr*8];
            float4 a1 = *(const float4*)&As[kk][tr*8 + 4];
            float4 b0 = *(const float4*)&Bs[kk][tc*8];
            float4 b1 = *(const float4*)&Bs[kk][tc*8 + 4];
            float av[8] = {a0.x, a0.y, a0.z, a0.w, a1.x, a1.y, a1.z, a1.w};
            #pragma unroll
            for (int ii = 0; ii < 8; ++ii) {
                acc[ii][0].x = fmaf(av[ii], b0.x, acc[ii][0].x);
                acc[ii][0].y = fmaf(av[ii], b0.y, acc[ii][0].y);
                acc[ii][0].z = fmaf(av[ii], b0.z, acc[ii][0].z);
                acc[ii][0].w = fmaf(av[ii], b0.w, acc[ii][0].w);
                acc[ii][1].x = fmaf(av[ii], b1.x, acc[ii][1].x);
                acc[ii][1].y = fmaf(av[ii], b1.y, acc[ii][1].y);
                acc[ii][1].z = fmaf(av[ii], b1.z, acc[ii][1].z);
                acc[ii][1].w = fmaf(av[ii], b1.w, acc[ii][1].w);
            }
        }
    }
    const int jbase = n0 + tc*8;
    float4 bb0 = *(const float4*)&bp[jbase];
    float4 bb1 = *(const float4*)&bp[jbase+4];
    #pragma unroll
    for (int ii = 0; ii < 8; ++ii) {
        int m = m0 + tr*8 + ii;
        float* p = out + m*256 + jbase;
        float4 o0, o1;
        o0.x = acc[ii][0].x + bb0.x; o0.y = acc[ii][0].y + bb0.y;
        o0.z = acc[ii][0].z + bb0.z; o0.w = acc[ii][0].w + bb0.w;
        o1.x = acc[ii][1].x + bb1.x; o1.y = acc[ii][1].y + bb1.y;
        o1.z = acc[ii][1].z + bb1.z; o1.w = acc[ii][1].w + bb1.w;
        *(float4*)p = o0;
        *(float4*)(p + 4) = o1;
    }
}

extern "C" void kernel_launch(void* const* d_in, const int* in_sizes, int n_in,
                              void* d_out, int out_size, void* d_ws, size_t ws_size,
                              hipStream_t stream)
{
    const float* x    = (const float*)d_in[0];
    const float* wqkv = (const float*)d_in[1];
    const float* qb   = (const float*)d_in[2];
    const float* vb   = (const float*)d_in[3];
    const float* ls   = (const float*)d_in[4];
    const float* w1   = (const float*)d_in[5];
    const float* b1   = (const float*)d_in[6];
    const float* w2   = (const float*)d_in[7];
    const float* wp   = (const float*)d_in[8];
    const float* bp   = (const float*)d_in[9];
    float* out = (float*)d_out;

    // Workspace layout (fits in 256 MiB):
    //   bias16T: 8192 floats (32 KB)
    //   Q, K, V: fp32, 16777216 floats each (64 MB each)
    //   AO:      bf16 packed as uint, 8388608 uints (32 MB)
    // total = 32 KB + 192 MB + 32 MB = 224.03 MB
    float* ws = (float*)d_ws;
    float* bias16T = ws;
    float* Q  = ws + 8192;
    float* K  = Q + 16777216;
    float* V  = K + 16777216;
    unsigned* AO = (unsigned*)(V + 16777216);

    cpb_kernel<<<961, 512, 0, stream>>>(w1, b1, w2, bias16T);
    qkv_gemm_kernel<<<dim3(512, 6), 256, 0, stream>>>(x, wqkv, qb, vb, Q, K, V);
    attn_kernel<<<2048, 256, 0, stream>>>(Q, K, V, bias16T, ls, AO);
    proj_gemm_kernel<<<dim3(512, 2), 256, 0, stream>>>(AO, wp, bp, out);
}

// Round 5
// 366.649 us; speedup vs baseline: 2.2747x; 2.2747x over previous
//
#include <hip/hip_runtime.h>
#include <hip/hip_bf16.h>

#define TBLSZ 961   // 31*31

typedef _Float16 half8 __attribute__((ext_vector_type(8)));
typedef float f32x4  __attribute__((ext_vector_type(4)));

// ---- fp16 helpers ----
__device__ __forceinline__ unsigned packh(float a, float b) {
    union { _Float16 h[2]; unsigned u; } r;
    r.h[0] = (_Float16)a; r.h[1] = (_Float16)b;
    return r.u;
}

// ---------------- fp32 -> fp16 conversion (x, w_qkv, w_proj) ----------------
__global__ __launch_bounds__(256) void cvt_kernel(
    const float4* __restrict__ x, const float4* __restrict__ wq, const float4* __restrict__ wp,
    uint2* __restrict__ xb, uint2* __restrict__ wb, uint2* __restrict__ wpb)
{
    const int NX = 4194304, NW = 49152, NP = 16384;
    const int stride = gridDim.x * 256;
    for (int i = blockIdx.x * 256 + threadIdx.x; i < NX + NW + NP; i += stride) {
        const float4* s; uint2* d; int j;
        if (i < NX)           { s = x;  d = xb;  j = i; }
        else if (i < NX + NW) { s = wq; d = wb;  j = i - NX; }
        else                  { s = wp; d = wpb; j = i - NX - NW; }
        float4 v = s[j];
        d[j] = make_uint2(packh(v.x, v.y), packh(v.z, v.w));
    }
}

// ---------------- CPB bias table: 16*sigmoid(MLP(coords)) -> [h][pos] ----------------
__global__ __launch_bounds__(512) void cpb_kernel(
    const float* __restrict__ w1, const float* __restrict__ b1,
    const float* __restrict__ w2, float* __restrict__ bias16T)
{
    const int pos = blockIdx.x;           // 0..960
    const int ia = pos / 31, ib = pos % 31;
    float va = (float)(ia - 15) * (16.0f / 15.0f);
    float vb = (float)(ib - 15) * (16.0f / 15.0f);
    float c0 = copysignf(log2f(fabsf(va) + 1.0f) * (1.0f / 3.0f), va);
    float c1 = copysignf(log2f(fabsf(vb) + 1.0f) * (1.0f / 3.0f), vb);
    const int t = threadIdx.x;
    __shared__ float hid[512];
    hid[t] = fmaxf(fmaf(w1[2*t], c0, fmaf(w1[2*t+1], c1, b1[t])), 0.0f);
    __syncthreads();
    const int h = t >> 6, l = t & 63;
    float p = 0.0f;
    #pragma unroll
    for (int i = 0; i < 8; ++i)
        p += w2[h*512 + 64*i + l] * hid[64*i + l];
    #pragma unroll
    for (int off = 32; off >= 1; off >>= 1)
        p += __shfl_down(p, off, 64);
    if (l == 0)
        bias16T[h*TBLSZ + pos] = 16.0f / (1.0f + __expf(-p));
}

// ---------------- QKV GEMM (fp16 MFMA): X[65536,256] @ W[768,256]^T + bias ----------
// Writes QB/KB as fp16 [bh][n][32]; V transposed VTB as fp16 [bh][dd][m(256)].
__global__ __launch_bounds__(256, 2) void qkv_mfma_kernel(
    const _Float16* __restrict__ XB, const _Float16* __restrict__ WB,
    const float* __restrict__ qb, const float* __restrict__ vbias,
    _Float16* __restrict__ QB, _Float16* __restrict__ KB,
    _Float16* __restrict__ VTB)
{
    const int t = threadIdx.x;
    const int lane = t & 63, wv = t >> 6;
    const int m0 = blockIdx.x * 128, n0 = blockIdx.y * 128;
    const int rbase = m0 + (wv >> 1) * 64;
    const int cbase = n0 + (wv & 1) * 64;
    const int l15 = lane & 15, lk = (lane >> 4) << 3;   // k offset (elems)

    f32x4 acc[4][4];
    #pragma unroll
    for (int i = 0; i < 4; ++i)
        #pragma unroll
        for (int j = 0; j < 4; ++j)
            acc[i][j] = (f32x4){0.f, 0.f, 0.f, 0.f};

    #pragma unroll
    for (int k0 = 0; k0 < 256; k0 += 32) {
        half8 af[4], bfr[4];
        #pragma unroll
        for (int rt = 0; rt < 4; ++rt)
            af[rt] = *(const half8*)(XB + (size_t)(rbase + rt*16 + l15) * 256 + k0 + lk);
        #pragma unroll
        for (int ct = 0; ct < 4; ++ct)
            bfr[ct] = *(const half8*)(WB + (size_t)(cbase + ct*16 + l15) * 256 + k0 + lk);
        #pragma unroll
        for (int rt = 0; rt < 4; ++rt)
            #pragma unroll
            for (int ct = 0; ct < 4; ++ct)
                acc[rt][ct] = __builtin_amdgcn_mfma_f32_16x16x32_f16(af[rt], bfr[ct], acc[rt][ct], 0, 0, 0);
    }

    const int which = n0 >> 8;   // 0=Q 1=K 2=V (uniform per block)
    #pragma unroll
    for (int ct = 0; ct < 4; ++ct) {
        const int j = cbase + ct*16 + l15;
        const int cin = j & 255, hh = cin >> 5, dd = cin & 31;
        float bb = 0.f;
        if (which == 0) bb = qb[cin];
        else if (which == 2) bb = vbias[cin];
        #pragma unroll
        for (int rt = 0; rt < 4; ++rt) {
            const int mb = rbase + rt*16 + ((lane >> 4) << 2);
            const int b = mb >> 8, nnb = mb & 255;
            f32x4 a = acc[rt][ct];
            if (which < 2) {
                _Float16* dstp = (which == 0 ? QB : KB)
                    + ((size_t)((b << 3) + hh) * 256 + nnb) * 32 + dd;
                #pragma unroll
                for (int reg = 0; reg < 4; ++reg)
                    dstp[reg * 32] = (_Float16)(a[reg] + bb);
            } else {
                _Float16* dstp = VTB
                    + ((size_t)((b << 3) + hh) * 32 + dd) * 256 + nnb;
                uint2 u;
                u.x = packh(a[0] + bb, a[1] + bb);
                u.y = packh(a[2] + bb, a[3] + bb);
                *(uint2*)dstp = u;
            }
        }
    }
}

// ---------------- Attention (fp16 MFMA): per (b,h) block, 4 waves x 64-row strips ----
#define PSTR 68   // P buffer row stride in halves (136B: 8B-aligned rows)
__global__ __launch_bounds__(256, 2) void attn_mfma_kernel(
    const _Float16* __restrict__ QB, const _Float16* __restrict__ KB,
    const _Float16* __restrict__ VTB, const float* __restrict__ bias16T,
    const float* __restrict__ logit_scale, _Float16* __restrict__ AO)
{
    __shared__ float tbl2[TBLSZ];
    __shared__ float rq[256], rk[256];
    __shared__ _Float16 pbuf[4][64 * PSTR];

    const int bh = blockIdx.x, h = bh & 7, b = bh >> 3;
    const int t = threadIdx.x;
    const float scale = __expf(fminf(logit_scale[h], 4.60517018598809136804f));
    const float off = scale + 16.0f;
    const float L2E = 1.44269504088896f;

    // stage bias table; fold: arg = L2E*(scale*cos + bias - off) + 14  (2^14 scaling
    // keeps P in fp16-normal range; cancels in P/sum; max P = 2^14 < 65504)
    for (int i = t; i < TBLSZ; i += 256)
        tbl2[i] = fmaf(bias16T[h*TBLSZ + i] - off, L2E, 14.0f);

    // per-row inverse norms from the SAME fp16 values the MFMA consumes
    // (4 x uint4 = 32 halves per row — full vector)
    {
        const _Float16* qrow = QB + ((size_t)bh*256 + t) * 32;
        const _Float16* krow = KB + ((size_t)bh*256 + t) * 32;
        float sq = 0.f, sk = 0.f;
        #pragma unroll
        for (int i = 0; i < 4; ++i) {
            union { uint4 v; _Float16 hh[8]; } a, c;
            a.v = *(const uint4*)(qrow + i*8);
            c.v = *(const uint4*)(krow + i*8);
            #pragma unroll
            for (int j = 0; j < 8; ++j) {
                float xq = (float)a.hh[j]; sq += xq*xq;
                float xk = (float)c.hh[j]; sk += xk*xk;
            }
        }
        rq[t] = rsqrtf(fmaxf(sq, 1e-24f)) * L2E;      // fold log2e
        rk[t] = rsqrtf(fmaxf(sk, 1e-24f)) * scale;    // fold logit scale
    }
    __syncthreads();

    const int lane = t & 63, wv = t >> 6;
    const int rbase = wv * 64;
    const int l15 = lane & 15, lk = (lane >> 4) << 3;
    _Float16* pb = pbuf[wv];

    // Q fragments (held in registers for all column blocks)
    half8 qf[4];
    #pragma unroll
    for (int rt = 0; rt < 4; ++rt)
        qf[rt] = *(const half8*)(QB + ((size_t)bh*256 + rbase + rt*16 + l15) * 32 + lk);

    // per-lane rq values for its 16 rows
    float rqv[4][4];
    #pragma unroll
    for (int rt = 0; rt < 4; ++rt)
        #pragma unroll
        for (int reg = 0; reg < 4; ++reg)
            rqv[rt][reg] = rq[rbase + rt*16 + ((lane >> 4) << 2) + reg];

    f32x4 oacc[4][2];
    #pragma unroll
    for (int i = 0; i < 4; ++i) { oacc[i][0] = (f32x4){0,0,0,0}; oacc[i][1] = (f32x4){0,0,0,0}; }
    float rs_[4][4];
    #pragma unroll
    for (int i = 0; i < 4; ++i)
        #pragma unroll
        for (int j = 0; j < 4; ++j) rs_[i][j] = 0.f;

    for (int cb = 0; cb < 4; ++cb) {
        // ---- S = Q K^T for 64x64 block ----
        f32x4 sacc[4][4];
        #pragma unroll
        for (int i = 0; i < 4; ++i)
            #pragma unroll
            for (int j = 0; j < 4; ++j) sacc[i][j] = (f32x4){0,0,0,0};
        half8 kf[4];
        #pragma unroll
        for (int ct = 0; ct < 4; ++ct)
            kf[ct] = *(const half8*)(KB + ((size_t)bh*256 + cb*64 + ct*16 + l15) * 32 + lk);
        #pragma unroll
        for (int rt = 0; rt < 4; ++rt)
            #pragma unroll
            for (int ct = 0; ct < 4; ++ct)
                sacc[rt][ct] = __builtin_amdgcn_mfma_f32_16x16x32_f16(qf[rt], kf[ct], sacc[rt][ct], 0, 0, 0);

        // ---- softmax (shifted exp2, no max pass) + P -> LDS (fp16) ----
        #pragma unroll
        for (int ct = 0; ct < 4; ++ct) {
            const float rkc = rk[cb*64 + ct*16 + l15];
            const int cterm = (15 - (cb*4 + ct)) * 31 + 15 - l15;
            #pragma unroll
            for (int rt = 0; rt < 4; ++rt) {
                const int pb_rt = ((rbase >> 4) + rt) * 31 + ((lane >> 4) << 2);
                const int prow = rt*16 + ((lane >> 4) << 2);
                #pragma unroll
                for (int reg = 0; reg < 4; ++reg) {
                    float e = exp2f(fmaf(sacc[rt][ct][reg], rqv[rt][reg] * rkc,
                                         tbl2[pb_rt + reg + cterm]));
                    rs_[rt][reg] += e;
                    pb[(prow + reg) * PSTR + ct*16 + l15] = (_Float16)e;
                }
            }
        }
        asm volatile("s_waitcnt lgkmcnt(0)" ::: "memory");
        __builtin_amdgcn_sched_barrier(0);

        // ---- O += P V for this 64-col block ----
        #pragma unroll
        for (int ks = 0; ks < 2; ++ks) {
            union { half8 v; uint2 u2[2]; } pp;
            half8 pf[4];
            #pragma unroll
            for (int rt = 0; rt < 4; ++rt) {
                const _Float16* src = pb + (rt*16 + l15) * PSTR + ks*32 + lk;
                pp.u2[0] = *(const uint2*)(src);
                pp.u2[1] = *(const uint2*)(src + 4);
                pf[rt] = pp.v;
            }
            #pragma unroll
            for (int dt = 0; dt < 2; ++dt) {
                half8 vf = *(const half8*)(VTB + ((size_t)bh*32 + dt*16 + l15) * 256
                                           + cb*64 + ks*32 + lk);
                #pragma unroll
                for (int rt = 0; rt < 4; ++rt)
                    oacc[rt][dt] = __builtin_amdgcn_mfma_f32_16x16x32_f16(pf[rt], vf, oacc[rt][dt], 0, 0, 0);
            }
        }
    }

    // ---- row sums across the 16 lanes sharing each row ----
    #pragma unroll
    for (int rt = 0; rt < 4; ++rt)
        #pragma unroll
        for (int reg = 0; reg < 4; ++reg) {
            float s = rs_[rt][reg];
            s += __shfl_xor(s, 1, 64);
            s += __shfl_xor(s, 2, 64);
            s += __shfl_xor(s, 4, 64);
            s += __shfl_xor(s, 8, 64);
            rs_[rt][reg] = 1.0f / s;
        }

    // ---- O normalize, repack via LDS, coalesced fp16 store ----
    float* ob = (float*)pb;    // 64 rows x stride 33 f32 (8448B <= 8704B buffer)
    #pragma unroll
    for (int rt = 0; rt < 4; ++rt)
        #pragma unroll
        for (int dt = 0; dt < 2; ++dt)
            #pragma unroll
            for (int reg = 0; reg < 4; ++reg)
                ob[(rt*16 + ((lane >> 4) << 2) + reg) * 33 + dt*16 + l15]
                    = oacc[rt][dt][reg] * rs_[rt][reg];
    asm volatile("s_waitcnt lgkmcnt(0)" ::: "memory");
    __builtin_amdgcn_sched_barrier(0);
    {
        const float* row = ob + lane * 33;
        unsigned u[16];
        #pragma unroll
        for (int i = 0; i < 16; ++i)
            u[i] = packh(row[2*i], row[2*i + 1]);
        _Float16* op = AO + ((size_t)b * 256 + rbase + lane) * 256 + h * 32;
        #pragma unroll
        for (int i = 0; i < 4; ++i)
            *(uint4*)(op + i * 8) = *(uint4*)(u + i * 4);
    }
}

// ---------------- Proj GEMM (fp16 MFMA): AO[65536,256] @ WP[256,256]^T + b -> fp32 ---
__global__ __launch_bounds__(256, 2) void proj_mfma_kernel(
    const _Float16* __restrict__ A, const _Float16* __restrict__ WPB,
    const float* __restrict__ bp, float* __restrict__ out)
{
    const int t = threadIdx.x;
    const int lane = t & 63, wv = t >> 6;
    const int m0 = blockIdx.x * 128, n0 = blockIdx.y * 128;
    const int rbase = m0 + (wv >> 1) * 64;
    const int cbase = n0 + (wv & 1) * 64;
    const int l15 = lane & 15, lk = (lane >> 4) << 3;

    f32x4 acc[4][4];
    #pragma unroll
    for (int i = 0; i < 4; ++i)
        #pragma unroll
        for (int j = 0; j < 4; ++j)
            acc[i][j] = (f32x4){0.f, 0.f, 0.f, 0.f};

    #pragma unroll
    for (int k0 = 0; k0 < 256; k0 += 32) {
        half8 af[4], bfr[4];
        #pragma unroll
        for (int rt = 0; rt < 4; ++rt)
            af[rt] = *(const half8*)(A + (size_t)(rbase + rt*16 + l15) * 256 + k0 + lk);
        #pragma unroll
        for (int ct = 0; ct < 4; ++ct)
            bfr[ct] = *(const half8*)(WPB + (size_t)(cbase + ct*16 + l15) * 256 + k0 + lk);
        #pragma unroll
        for (int rt = 0; rt < 4; ++rt)
            #pragma unroll
            for (int ct = 0; ct < 4; ++ct)
                acc[rt][ct] = __builtin_amdgcn_mfma_f32_16x16x32_f16(af[rt], bfr[ct], acc[rt][ct], 0, 0, 0);
    }

    #pragma unroll
    for (int ct = 0; ct < 4; ++ct) {
        const int j = cbase + ct*16 + l15;
        const float bb = bp[j];
        #pragma unroll
        for (int rt = 0; rt < 4; ++rt) {
            const int mb = rbase + rt*16 + ((lane >> 4) << 2);
            #pragma unroll
            for (int reg = 0; reg < 4; ++reg)
                out[(size_t)(mb + reg) * 256 + j] = acc[rt][ct][reg] + bb;
        }
    }
}

extern "C" void kernel_launch(void* const* d_in, const int* in_sizes, int n_in,
                              void* d_out, int out_size, void* d_ws, size_t ws_size,
                              hipStream_t stream)
{
    const float* x    = (const float*)d_in[0];
    const float* wqkv = (const float*)d_in[1];
    const float* qb   = (const float*)d_in[2];
    const float* vb   = (const float*)d_in[3];
    const float* ls   = (const float*)d_in[4];
    const float* w1   = (const float*)d_in[5];
    const float* b1   = (const float*)d_in[6];
    const float* w2   = (const float*)d_in[7];
    const float* wp   = (const float*)d_in[8];
    const float* bp   = (const float*)d_in[9];
    float* out = (float*)d_out;

    // Workspace (bytes from base; total ~168.3 MB — fits known-good 224 MB):
    char* wsb = (char*)d_ws;
    float*     bias16T = (float*)wsb;                    //    32768
    _Float16*  XB  = (_Float16*)(wsb + 32768);           // 33554432
    _Float16*  WB  = (_Float16*)(wsb + 33587200);        //   393216
    _Float16*  WPB = (_Float16*)(wsb + 33980416);        //   131072
    _Float16*  QBp = (_Float16*)(wsb + 34111488);        // 33554432
    _Float16*  KBp = (_Float16*)(wsb + 67665920);        // 33554432
    _Float16*  VTB = (_Float16*)(wsb + 101220352);       // 33554432
    _Float16*  AO  = (_Float16*)(wsb + 134774784);       // 33554432

    cvt_kernel<<<2048, 256, 0, stream>>>((const float4*)x, (const float4*)wqkv, (const float4*)wp,
                                         (uint2*)XB, (uint2*)WB, (uint2*)WPB);
    cpb_kernel<<<961, 512, 0, stream>>>(w1, b1, w2, bias16T);
    qkv_mfma_kernel<<<dim3(512, 6), 256, 0, stream>>>(XB, WB, qb, vb, QBp, KBp, VTB);
    attn_mfma_kernel<<<2048, 256, 0, stream>>>(QBp, KBp, VTB, bias16T, ls, AO);
    proj_mfma_kernel<<<dim3(512, 2), 256, 0, stream>>>(AO, WPB, bp, out);
}